// Round 7
// baseline (376.059 us; speedup 1.0000x reference)
//
#include <hip/hip_runtime.h>
#include <hip/hip_bf16.h>

// VectorQuantizer: B=16, D=256, T=2048, K=1024, N=B*T=32768
// inputs: [B, D, T] fp32 ; embeddings: [K, D] fp32
// outputs (concat, fp32): quantized_st [B,D,T] | loss | e_latent | q_latent | indices [32768]
#define NB 16
#define ND 256
#define NT 2048
#define NK 1024
#define NN (NB * NT)
#define QSIZE (NB * ND * NT)
#define SCL_OFF QSIZE
#define IDX_OFF (QSIZE + 3)
// bf16-split score error ~3e-6 est / ~1e-5 worst; TAU=4e-5 -> ~2000 rows refined exactly.
#define TAU 4.0e-5f
#define NSLICE 4          // K-split: 256 codes / slice, 16 chunks of 16 codes

// ws layout (bytes) — 2.33 MB total (ws_size >= 2.38 MB proven in round 5); ET optional
#define WS_PART  0         // double[1024]
#define WS_E2F   8192      // float[1024]
#define WS_E2D   12288     // double[1024]
#define WS_B1S   20480     // float[4][32768] per-slice best
#define WS_B2S   544768    // float[4][32768] per-slice second-best
#define WS_I1S   1069056   // ushort[4][32768] per-slice argmin
#define WS_BPACK 1331200   // 1 MB: B-fragment-packed E, bf16 hi|lo
#define WS_ET    2379776   // 1 MB: float ET[256][1024] (optional, coalesced refine)
#define WS_NEED_ET (WS_ET + 1048576)

typedef __attribute__((ext_vector_type(8))) short bf16x8;
typedef __attribute__((ext_vector_type(4))) float f32x4;
#define MFMA16(a, b, c) __builtin_amdgcn_mfma_f32_16x16x32_bf16(a, b, c, 0, 0, 0)

__device__ inline void bf16split(float v, short& hi, short& lo) {
    union { __hip_bfloat16 b; short s; } uh, ul;
    uh.b = __float2bfloat16(v);
    float hf = __bfloat162float(uh.b);
    ul.b = __float2bfloat16(v - hf);
    hi = uh.s; lo = ul.s;
}

// ---------------- Fused prep: e2[k] (fp64+fp32) + optional ET transpose + Bpack.
// Block k = one code row. Threads 0-31 pack B-fragments via shfl from the row already loaded.
__global__ __launch_bounds__(64) void vq_prep(const float4* __restrict__ E4,
                                              double* __restrict__ e2d,
                                              float* __restrict__ e2f,
                                              float* __restrict__ ET, int use_et,
                                              uint4* __restrict__ Bp4) {
    const int k = blockIdx.x;
    const int lane = threadIdx.x;
    float4 v = E4[k * 64 + lane];
    if (use_et) {
        ET[(size_t)(4 * lane + 0) * NK + k] = v.x;
        ET[(size_t)(4 * lane + 1) * NK + k] = v.y;
        ET[(size_t)(4 * lane + 2) * NK + k] = v.z;
        ET[(size_t)(4 * lane + 3) * NK + k] = v.w;
    }
    // Bpack: thread t<32 (ds=t>>2, q=t&3) packs d = ds*32+q*8+{0..7} = row lanes 2t, 2t+1.
    float4 a, b2v;
    a.x = __shfl(v.x, 2 * lane, 64); a.y = __shfl(v.y, 2 * lane, 64);
    a.z = __shfl(v.z, 2 * lane, 64); a.w = __shfl(v.w, 2 * lane, 64);
    b2v.x = __shfl(v.x, 2 * lane + 1, 64); b2v.y = __shfl(v.y, 2 * lane + 1, 64);
    b2v.z = __shfl(v.z, 2 * lane + 1, 64); b2v.w = __shfl(v.w, 2 * lane + 1, 64);
    if (lane < 32) {
        const int ds = lane >> 2, q = lane & 3;
        const int cc = k >> 4;
        const int fl = q * 16 + (k & 15);
        float vals[8] = {a.x, a.y, a.z, a.w, b2v.x, b2v.y, b2v.z, b2v.w};
        union { short s[8]; uint4 u; } hi, lo;
        #pragma unroll
        for (int j = 0; j < 8; ++j) bf16split(vals[j], hi.s[j], lo.s[j]);
        Bp4[(size_t)cc * 1024 + ds * 64 + fl]       = hi.u;
        Bp4[(size_t)cc * 1024 + 512 + ds * 64 + fl] = lo.u;
    }
    double s = (double)v.x * v.x + (double)v.y * v.y + (double)v.z * v.z + (double)v.w * v.w;
    #pragma unroll
    for (int off = 32; off; off >>= 1) s += __shfl_down(s, off, 64);
    if (lane == 0) { e2d[k] = s; e2f[k] = (float)s; }
}

// ---------------- Pass 1: 4-way K-split MFMA bf16-split distance GEMM + per-slice argmin.
// grid 1024: slice = bid&3 (256 codes = 16 chunks), rows = (bid>>2)*128.
// 4 blocks/CU (LDS 128KB, VGPR<=128) -> 16 waves/CU: LDS/MFMA/barrier pipes overlap.
__global__ __launch_bounds__(256, 4) void vq_pass1(const float* __restrict__ X,
                                                   const uint4* __restrict__ Bp4,
                                                   const float* __restrict__ e2f,
                                                   float* __restrict__ b1s,
                                                   float* __restrict__ b2s,
                                                   unsigned short* __restrict__ i1s) {
    __shared__ uint4 Bl4[2][1024];   // 32 KB double buffer, chunk = 16 codes
    const int tid   = threadIdx.x;
    const int lane  = tid & 63;
    const int w     = tid >> 6;
    const int slice = blockIdx.x & 3;
    const int n0    = (blockIdx.x >> 2) * 128;
    const int b     = n0 >> 11;
    const int t0    = n0 & (NT - 1);
    const int m16   = lane & 15;
    const int q     = lane >> 4;
    const uint4* Bps = Bp4 + (size_t)slice * 16384;   // 16 chunks x 1024 uint4

    // A fragments: lane holds A[m=lane&15][k=q*8+j] for d = ds*32 + q*8 + j.
    bf16x8 ah[2][8], al[2][8];
    const float* Xb = X + (size_t)b * (ND * NT);
    #pragma unroll
    for (int t = 0; t < 2; ++t) {
        const int trow = t0 + w * 32 + t * 16 + m16;
        #pragma unroll
        for (int ds = 0; ds < 8; ++ds) {
            #pragma unroll
            for (int j = 0; j < 8; ++j) {
                const int d = ds * 32 + q * 8 + j;
                float v = Xb[(size_t)d * NT + trow];
                short h, l; bf16split(v, h, l);
                ah[t][ds][j] = h; al[t][ds][j] = l;
            }
        }
    }

    float b1[2][4], b2[2][4]; int i1[2][4];
    #pragma unroll
    for (int t = 0; t < 2; ++t)
        #pragma unroll
        for (int r = 0; r < 4; ++r) { b1[t][r] = 3e38f; b2[t][r] = 3e38f; i1[t][r] = 0; }

    uint4 pre[4];
    #pragma unroll
    for (int i = 0; i < 4; ++i) pre[i] = Bps[tid + 256 * i];
    #pragma unroll
    for (int i = 0; i < 4; ++i) Bl4[0][tid + 256 * i] = pre[i];
    __syncthreads();

    for (int cc = 0; cc < 16; ++cc) {
        const bf16x8* Bf = (const bf16x8*)Bl4[cc & 1];
        if (cc < 15) {
            #pragma unroll
            for (int i = 0; i < 4; ++i) pre[i] = Bps[(size_t)(cc + 1) * 1024 + tid + 256 * i];
        }
        f32x4 hh0 = {0.f,0.f,0.f,0.f}, lh0 = {0.f,0.f,0.f,0.f}, hl0 = {0.f,0.f,0.f,0.f};
        f32x4 hh1 = {0.f,0.f,0.f,0.f}, lh1 = {0.f,0.f,0.f,0.f}, hl1 = {0.f,0.f,0.f,0.f};
        #pragma unroll
        for (int ds = 0; ds < 8; ++ds) {
            bf16x8 bh = Bf[ds * 64 + lane];
            bf16x8 bl = Bf[512 + ds * 64 + lane];
            hh0 = MFMA16(ah[0][ds], bh, hh0);   // 6 independent chains
            hh1 = MFMA16(ah[1][ds], bh, hh1);
            lh0 = MFMA16(al[0][ds], bh, lh0);
            lh1 = MFMA16(al[1][ds], bh, lh1);
            hl0 = MFMA16(ah[0][ds], bl, hl0);
            hl1 = MFMA16(ah[1][ds], bl, hl1);
        }
        if (cc < 15) {
            #pragma unroll
            for (int i = 0; i < 4; ++i) Bl4[(cc + 1) & 1][tid + 256 * i] = pre[i];
            __syncthreads();
        }
        const int  code = slice * 256 + cc * 16 + m16;
        const float e2v = e2f[code];
        #pragma unroll
        for (int r = 0; r < 4; ++r) {
            float s0 = e2v - 2.0f * (hh0[r] + lh0[r] + hl0[r]);
            if (s0 < b1[0][r]) { b2[0][r] = b1[0][r]; b1[0][r] = s0; i1[0][r] = code; }
            else if (s0 < b2[0][r]) b2[0][r] = s0;
            float s1 = e2v - 2.0f * (hh1[r] + lh1[r] + hl1[r]);
            if (s1 < b1[1][r]) { b2[1][r] = b1[1][r]; b1[1][r] = s1; i1[1][r] = code; }
            else if (s1 < b2[1][r]) b2[1][r] = s1;
        }
    }

    // Reduce across the 16 code-classes; write per-slice candidates.
    #pragma unroll
    for (int t = 0; t < 2; ++t) {
        #pragma unroll
        for (int r = 0; r < 4; ++r) {
            float B1 = b1[t][r], B2 = b2[t][r]; int I1 = i1[t][r];
            #pragma unroll
            for (int mm = 1; mm < 16; mm <<= 1) {
                float o1 = __shfl_xor(B1, mm, 16);
                float o2 = __shfl_xor(B2, mm, 16);
                int   oi = __shfl_xor(I1, mm, 16);
                if (o1 < B1 || (o1 == B1 && oi < I1)) { B2 = fminf(B1, o2); B1 = o1; I1 = oi; }
                else B2 = fminf(B2, o1);
            }
            if (m16 == 0) {
                int n = n0 + w * 32 + t * 16 + q * 4 + r;   // C/D: row = quad*4 + reg
                size_t s = (size_t)slice * NN + n;
                b1s[s] = B1; b2s[s] = B2; i1s[s] = (unsigned short)I1;
            }
        }
    }
}

// ---------------- Fused merge + refine. Block handles 64 rows: wave 0 merges the 4 slices
// (writes final indices), ballot-compacts ambiguous rows to LDS, then all 4 waves refine
// them in exact fp64, 4 rows/pass sharing E reads. No global atomics, no list kernel.
__global__ __launch_bounds__(256, 2) void vq_refine(const float* __restrict__ X,
                                                    const float4* __restrict__ E4,
                                                    const float* __restrict__ ET, int use_et,
                                                    const double* __restrict__ e2d,
                                                    const float* __restrict__ b1s,
                                                    const float* __restrict__ b2s,
                                                    const unsigned short* __restrict__ i1s,
                                                    float* __restrict__ out) {
    __shared__ double xs[4][256];
    __shared__ double sm_s[4][4];
    __shared__ int    sm_k[4][4];
    __shared__ int    lds_list[64];
    __shared__ int    lds_cnt;
    const int tid = threadIdx.x;
    const int nb0 = blockIdx.x * 64;

    if (tid < 64) {
        const int n = nb0 + tid;
        float B1 = b1s[n], B2 = b2s[n]; int I1 = i1s[n];
        #pragma unroll
        for (int s = 1; s < NSLICE; ++s) {
            float c1 = b1s[(size_t)s * NN + n], c2 = b2s[(size_t)s * NN + n];
            int   ci = i1s[(size_t)s * NN + n];
            if (c1 < B1) { B2 = fminf(B1, c2); B1 = c1; I1 = ci; }  // strict <: earlier slice wins ties
            else          B2 = fminf(B2, c1);
        }
        out[IDX_OFF + n] = (float)I1;
        const bool flag = (B2 - B1 < TAU);
        unsigned long long mask = __ballot(flag);
        int pos = __popcll(mask & ((1ull << tid) - 1ull));
        if (flag) lds_list[pos] = n;
        if (tid == 0) lds_cnt = (int)__popcll(mask);
    }
    __syncthreads();
    const int m = lds_cnt;

    for (int j0 = 0; j0 < m; j0 += 4) {
        int nrow[4];
        #pragma unroll
        for (int g = 0; g < 4; ++g) {
            int j = j0 + g;
            nrow[g] = lds_list[j < m ? j : m - 1];
        }
        #pragma unroll
        for (int g = 0; g < 4; ++g) {
            int n = nrow[g]; int bb = n >> 11; int tt = n & (NT - 1);
            xs[g][tid] = (double)X[((size_t)bb * ND + tid) * NT + tt];
        }
        __syncthreads();
        double acc[4][4];   // [kk][g]
        #pragma unroll
        for (int kk = 0; kk < 4; ++kk)
            #pragma unroll
            for (int g = 0; g < 4; ++g) acc[kk][g] = 0.0;
        if (use_et) {
            #pragma unroll 2
            for (int dd = 0; dd < 256; ++dd) {
                float e0 = ET[(size_t)dd * NK +   0 + tid];   // coalesced
                float e1 = ET[(size_t)dd * NK + 256 + tid];
                float e2 = ET[(size_t)dd * NK + 512 + tid];
                float e3 = ET[(size_t)dd * NK + 768 + tid];
                #pragma unroll
                for (int g = 0; g < 4; ++g) {
                    double xv = xs[g][dd];
                    acc[0][g] += xv * (double)e0;
                    acc[1][g] += xv * (double)e1;
                    acc[2][g] += xv * (double)e2;
                    acc[3][g] += xv * (double)e3;
                }
            }
        } else {
            for (int dq = 0; dq < 64; ++dq) {
                #pragma unroll
                for (int kk = 0; kk < 4; ++kk) {
                    float4 ev = E4[(size_t)(kk * 256 + tid) * 64 + dq];
                    #pragma unroll
                    for (int g = 0; g < 4; ++g)
                        acc[kk][g] += xs[g][dq*4+0] * (double)ev.x + xs[g][dq*4+1] * (double)ev.y
                                    + xs[g][dq*4+2] * (double)ev.z + xs[g][dq*4+3] * (double)ev.w;
                }
            }
        }
        #pragma unroll
        for (int g = 0; g < 4; ++g) {
            double bs = 1e300; int bk = 0x7fffffff;
            #pragma unroll
            for (int kk = 0; kk < 4; ++kk) {
                int k = kk * 256 + tid;
                double s = e2d[k] - 2.0 * acc[kk][g];
                if (s < bs) { bs = s; bk = k; }           // kk ascending: first-index wins
            }
            #pragma unroll
            for (int mm = 1; mm < 64; mm <<= 1) {
                double os = __shfl_xor(bs, mm, 64);
                int    ok = __shfl_xor(bk, mm, 64);
                if (os < bs || (os == bs && ok < bk)) { bs = os; bk = ok; }
            }
            if ((tid & 63) == 0) { sm_s[tid >> 6][g] = bs; sm_k[tid >> 6][g] = bk; }
        }
        __syncthreads();
        if (tid < 4) {
            double Bv = 1e300; int Kv = 0x7fffffff;
            for (int ww = 0; ww < 4; ++ww) {
                double s2 = sm_s[ww][tid]; int k2 = sm_k[ww][tid];
                if (s2 < Bv || (s2 == Bv && k2 < Kv)) { Bv = s2; Kv = k2; }
            }
            if (j0 + tid < m) out[IDX_OFF + nrow[tid]] = (float)Kv;
        }
        __syncthreads();
    }
}

// ---------------- Gather via LDS tile-transpose + per-block MSE partial
__global__ __launch_bounds__(256) void vq_gather(const float* __restrict__ X,
                                                 const float4* __restrict__ E4,
                                                 float* __restrict__ out,
                                                 double* __restrict__ part) {
    __shared__ float Eq[32 * 257];
    __shared__ double sm[4];
    const int bt = blockIdx.x;
    const int b  = bt >> 6;
    const int t0 = (bt & 63) << 5;
    const float* irowf = out + IDX_OFF + b * NT + t0;   // float-encoded indices (exact <=1024)
    {
        const int r  = threadIdx.x >> 3;
        const int l8 = threadIdx.x & 7;
        const int id = (int)irowf[r];
        const float4* er = E4 + (size_t)id * 64;
        #pragma unroll
        for (int it = 0; it < 8; ++it) {
            int c = l8 + (it << 3);
            float4 v = er[c];
            float* p = &Eq[r * 257 + 4 * c];
            p[0] = v.x; p[1] = v.y; p[2] = v.z; p[3] = v.w;
        }
    }
    __syncthreads();
    const int tw = threadIdx.x & 31;
    const int dg = threadIdx.x >> 5;
    double ls = 0.0;
    #pragma unroll 8
    for (int it = 0; it < 32; ++it) {
        const int d = dg + (it << 3);
        const float qv = Eq[tw * 257 + d];
        const size_t off = ((size_t)b * ND + d) * NT + t0 + tw;
        const float x = X[off];
        out[off] = x + (qv - x);             // straight-through, reference rounding
        const double df = (double)qv - (double)x;
        ls = fma(df, df, ls);
    }
    #pragma unroll
    for (int o = 32; o; o >>= 1) ls += __shfl_down(ls, o, 64);
    if ((threadIdx.x & 63) == 0) sm[threadIdx.x >> 6] = ls;
    __syncthreads();
    if (threadIdx.x == 0) part[bt] = sm[0] + sm[1] + sm[2] + sm[3];
}

// ---------------- Finalize: reduce 1024 partials, write scalars
__global__ __launch_bounds__(256) void vq_final(const double* __restrict__ part,
                                                float* __restrict__ out) {
    __shared__ double sm[4];
    const int tid = threadIdx.x;
    double s = part[tid] + part[tid + 256] + part[tid + 512] + part[tid + 768];
    #pragma unroll
    for (int o = 32; o; o >>= 1) s += __shfl_down(s, o, 64);
    if ((tid & 63) == 0) sm[tid >> 6] = s;
    __syncthreads();
    if (tid == 0) {
        double mse = (sm[0] + sm[1] + sm[2] + sm[3]) * (1.0 / (double)QSIZE);
        out[SCL_OFF + 0] = (float)(1.25 * mse);
        out[SCL_OFF + 1] = (float)mse;
        out[SCL_OFF + 2] = (float)mse;
    }
}

extern "C" void kernel_launch(void* const* d_in, const int* in_sizes, int n_in,
                              void* d_out, int out_size, void* d_ws, size_t ws_size,
                              hipStream_t stream) {
    const float* X = (const float*)d_in[0];   // [16, 256, 2048]
    const float* E = (const float*)d_in[1];   // [1024, 256]
    float* out = (float*)d_out;

    char* ws = (char*)d_ws;
    double* part  = (double*)(ws + WS_PART);
    float*  e2f   = (float*) (ws + WS_E2F);
    double* e2d   = (double*)(ws + WS_E2D);
    float*  b1s   = (float*) (ws + WS_B1S);
    float*  b2s   = (float*) (ws + WS_B2S);
    unsigned short* i1s = (unsigned short*)(ws + WS_I1S);
    uint4*  bpack = (uint4*) (ws + WS_BPACK);
    float*  et    = (float*) (ws + WS_ET);
    const int use_et = (ws_size >= (size_t)WS_NEED_ET) ? 1 : 0;

    vq_prep  <<<NK, 64, 0, stream>>>((const float4*)E, e2d, e2f, et, use_et, bpack);
    vq_pass1 <<<(NN / 128) * NSLICE, 256, 0, stream>>>(X, bpack, e2f, b1s, b2s, i1s);
    vq_refine<<<NN / 64, 256, 0, stream>>>(X, (const float4*)E, et, use_et, e2d,
                                           b1s, b2s, i1s, out);
    vq_gather<<<NB * (NT / 32), 256, 0, stream>>>(X, (const float4*)E, out, part);
    vq_final <<<1, 256, 0, stream>>>(part, out);
}

// Round 8
// 259.982 us; speedup vs baseline: 1.4465x; 1.4465x over previous
//
#include <hip/hip_runtime.h>
#include <hip/hip_bf16.h>

// VectorQuantizer: B=16, D=256, T=2048, K=1024, N=B*T=32768
// inputs: [B, D, T] fp32 ; embeddings: [K, D] fp32
// outputs (concat, fp32): quantized_st [B,D,T] | loss | e_latent | q_latent | indices [32768]
#define NB 16
#define ND 256
#define NT 2048
#define NK 1024
#define NN (NB * NT)
#define QSIZE (NB * ND * NT)
#define SCL_OFF QSIZE
#define IDX_OFF (QSIZE + 3)
// bf16-split score error <=~4e-6 worst; TAU=4e-5 (>=5x headroom over 2*eps) -> ~2000 rows refined.
#define TAU 4.0e-5f
#define NSLICE 4          // K-split: 256 codes / slice = 16 chunks of 16 codes

// ws layout (bytes) — 2.08 MB total; proven safe ws_size >= 2.38 MB (round 7 ran this much).
// ET (refine's transposed E) OVERLAYS Bpack: Bpack dead after pass1, ET written in merge.
#define WS_E2F   0         // float[1024]
#define WS_E2D   4096      // double[1024]
#define WS_CNT   12288     // int (+pad)
#define WS_PART  12352     // double[1024]
#define WS_LIST  20544     // ushort[32768]
#define WS_B1S   86080     // float[4][32768] per-slice best
#define WS_I1S   610368    // ushort[4][32768] per-slice argmin
#define WS_M12   872512    // ushort[4][32768] per-slice quantized margin (b2-b1)/1e-8, saturating
#define WS_BPACK 1134656   // 1 MB: B-fragment-packed E (bf16 hi|lo); ET overlays after pass1

typedef __attribute__((ext_vector_type(8))) short bf16x8;
typedef __attribute__((ext_vector_type(4))) float f32x4;
#define MFMA16(a, b, c) __builtin_amdgcn_mfma_f32_16x16x32_bf16(a, b, c, 0, 0, 0)

__device__ inline void bf16split(float v, short& hi, short& lo) {
    union { __hip_bfloat16 b; short s; } uh, ul;
    uh.b = __float2bfloat16(v);
    float hf = __bfloat162float(uh.b);
    ul.b = __float2bfloat16(v - hf);
    hi = uh.s; lo = ul.s;
}

// ---------------- Fused prep: e2[k] (fp64+fp32) + Bpack; zero refine counter.
__global__ __launch_bounds__(64) void vq_prep(const float4* __restrict__ E4,
                                              double* __restrict__ e2d,
                                              float* __restrict__ e2f,
                                              uint4* __restrict__ Bp4,
                                              int* __restrict__ cnt) {
    const int k = blockIdx.x;
    const int lane = threadIdx.x;
    float4 v = E4[k * 64 + lane];
    // Bpack: thread t<32 (ds=t>>2, q=t&3) packs d = ds*32+q*8+{0..7} = row lanes 2t, 2t+1.
    float4 a, b2v;
    a.x = __shfl(v.x, 2 * lane, 64); a.y = __shfl(v.y, 2 * lane, 64);
    a.z = __shfl(v.z, 2 * lane, 64); a.w = __shfl(v.w, 2 * lane, 64);
    b2v.x = __shfl(v.x, 2 * lane + 1, 64); b2v.y = __shfl(v.y, 2 * lane + 1, 64);
    b2v.z = __shfl(v.z, 2 * lane + 1, 64); b2v.w = __shfl(v.w, 2 * lane + 1, 64);
    if (lane < 32) {
        const int ds = lane >> 2, q = lane & 3;
        const int cc = k >> 4;
        const int fl = q * 16 + (k & 15);
        float vals[8] = {a.x, a.y, a.z, a.w, b2v.x, b2v.y, b2v.z, b2v.w};
        union { short s[8]; uint4 u; } hi, lo;
        #pragma unroll
        for (int j = 0; j < 8; ++j) bf16split(vals[j], hi.s[j], lo.s[j]);
        Bp4[(size_t)cc * 1024 + ds * 64 + fl]       = hi.u;
        Bp4[(size_t)cc * 1024 + 512 + ds * 64 + fl] = lo.u;
    }
    double s = (double)v.x * v.x + (double)v.y * v.y + (double)v.z * v.z + (double)v.w * v.w;
    #pragma unroll
    for (int off = 32; off; off >>= 1) s += __shfl_down(s, off, 64);
    if (lane == 0) { e2d[k] = s; e2f[k] = (float)s; }
    if (k == 0 && lane == 0) cnt[0] = 0;
}

// ---------------- Pass 1: 4-way K-split MFMA bf16-split distance GEMM + per-slice argmin.
// grid 1024: slice = bid&3 (16 chunks), rows = (bid>>2)*128. bounds(256,2) — do NOT force
// 4 waves/EU: round 7 proved that caps VGPR at 64 and spills (754 MB scratch traffic).
// VGPR ~108 naturally fits 4 waves/SIMD (4x108<=512) -> up to 4 blocks/CU co-resident.
__global__ __launch_bounds__(256, 2) void vq_pass1(const float* __restrict__ X,
                                                   const uint4* __restrict__ Bp4,
                                                   const float* __restrict__ e2f,
                                                   float* __restrict__ b1s,
                                                   unsigned short* __restrict__ i1s,
                                                   unsigned short* __restrict__ m12s) {
    __shared__ uint4 Bl4[2][1024];   // 32 KB double buffer, chunk = 16 codes
    const int tid   = threadIdx.x;
    const int lane  = tid & 63;
    const int w     = tid >> 6;
    const int slice = blockIdx.x & 3;
    const int n0    = (blockIdx.x >> 2) * 128;
    const int b     = n0 >> 11;
    const int t0    = n0 & (NT - 1);
    const int m16   = lane & 15;
    const int q     = lane >> 4;
    const uint4* Bps = Bp4 + (size_t)slice * 16384;   // 16 chunks x 1024 uint4

    // A fragments: lane holds A[m=lane&15][k=q*8+j] for d = ds*32 + q*8 + j.
    bf16x8 ah[2][8], al[2][8];
    const float* Xb = X + (size_t)b * (ND * NT);
    #pragma unroll
    for (int t = 0; t < 2; ++t) {
        const int trow = t0 + w * 32 + t * 16 + m16;
        #pragma unroll
        for (int ds = 0; ds < 8; ++ds) {
            #pragma unroll
            for (int j = 0; j < 8; ++j) {
                const int d = ds * 32 + q * 8 + j;
                float v = Xb[(size_t)d * NT + trow];
                short h, l; bf16split(v, h, l);
                ah[t][ds][j] = h; al[t][ds][j] = l;
            }
        }
    }

    float b1[2][4], b2[2][4]; int i1[2][4];
    #pragma unroll
    for (int t = 0; t < 2; ++t)
        #pragma unroll
        for (int r = 0; r < 4; ++r) { b1[t][r] = 3e38f; b2[t][r] = 3e38f; i1[t][r] = 0; }

    uint4 pre[4];
    #pragma unroll
    for (int i = 0; i < 4; ++i) pre[i] = Bps[tid + 256 * i];
    #pragma unroll
    for (int i = 0; i < 4; ++i) Bl4[0][tid + 256 * i] = pre[i];
    __syncthreads();

    for (int cc = 0; cc < 16; ++cc) {
        const bf16x8* Bf = (const bf16x8*)Bl4[cc & 1];
        if (cc < 15) {
            #pragma unroll
            for (int i = 0; i < 4; ++i) pre[i] = Bps[(size_t)(cc + 1) * 1024 + tid + 256 * i];
        }
        f32x4 hh0 = {0.f,0.f,0.f,0.f}, lh0 = {0.f,0.f,0.f,0.f}, hl0 = {0.f,0.f,0.f,0.f};
        f32x4 hh1 = {0.f,0.f,0.f,0.f}, lh1 = {0.f,0.f,0.f,0.f}, hl1 = {0.f,0.f,0.f,0.f};
        #pragma unroll
        for (int ds = 0; ds < 8; ++ds) {
            bf16x8 bh = Bf[ds * 64 + lane];
            bf16x8 bl = Bf[512 + ds * 64 + lane];
            hh0 = MFMA16(ah[0][ds], bh, hh0);   // 6 independent chains
            hh1 = MFMA16(ah[1][ds], bh, hh1);
            lh0 = MFMA16(al[0][ds], bh, lh0);
            lh1 = MFMA16(al[1][ds], bh, lh1);
            hl0 = MFMA16(ah[0][ds], bl, hl0);
            hl1 = MFMA16(ah[1][ds], bl, hl1);
        }
        if (cc < 15) {
            #pragma unroll
            for (int i = 0; i < 4; ++i) Bl4[(cc + 1) & 1][tid + 256 * i] = pre[i];
            __syncthreads();
        }
        const int  code = slice * 256 + cc * 16 + m16;
        const float e2v = e2f[code];
        #pragma unroll
        for (int r = 0; r < 4; ++r) {
            float s0 = e2v - 2.0f * (hh0[r] + lh0[r] + hl0[r]);
            if (s0 < b1[0][r]) { b2[0][r] = b1[0][r]; b1[0][r] = s0; i1[0][r] = code; }
            else if (s0 < b2[0][r]) b2[0][r] = s0;
            float s1 = e2v - 2.0f * (hh1[r] + lh1[r] + hl1[r]);
            if (s1 < b1[1][r]) { b2[1][r] = b1[1][r]; b1[1][r] = s1; i1[1][r] = code; }
            else if (s1 < b2[1][r]) b2[1][r] = s1;
        }
    }

    // Reduce across the 16 code-classes; write per-slice candidates (margin quantized).
    #pragma unroll
    for (int t = 0; t < 2; ++t) {
        #pragma unroll
        for (int r = 0; r < 4; ++r) {
            float B1 = b1[t][r], B2 = b2[t][r]; int I1 = i1[t][r];
            #pragma unroll
            for (int mm = 1; mm < 16; mm <<= 1) {
                float o1 = __shfl_xor(B1, mm, 16);
                float o2 = __shfl_xor(B2, mm, 16);
                int   oi = __shfl_xor(I1, mm, 16);
                if (o1 < B1 || (o1 == B1 && oi < I1)) { B2 = fminf(B1, o2); B1 = o1; I1 = oi; }
                else B2 = fminf(B2, o1);
            }
            if (m16 == 0) {
                int n = n0 + w * 32 + t * 16 + q * 4 + r;   // C/D: row = quad*4 + reg
                size_t s = (size_t)slice * NN + n;
                b1s[s] = B1;
                i1s[s] = (unsigned short)I1;
                // margin in 1e-8 units, saturating: err 1e-8 << TAU; saturation only >6.5e-4
                m12s[s] = (unsigned short)fminf(65535.0f, rintf((B2 - B1) * 1.0e8f));
            }
        }
    }
}

// ---------------- Merge slices -> final index + compacted refine list; also build ET
// (E transposed, overlays Bpack which is dead after pass1) for coalesced refine reads.
__global__ __launch_bounds__(256) void vq_merge(const float4* __restrict__ E4,
                                                const float* __restrict__ b1s,
                                                const unsigned short* __restrict__ i1s,
                                                const unsigned short* __restrict__ m12s,
                                                int* __restrict__ cnt,
                                                unsigned short* __restrict__ list,
                                                float* __restrict__ ET,
                                                float* __restrict__ out) {
    const int tid = threadIdx.x;
    const int gid = blockIdx.x * 256 + tid;       // 0..32767
    // ET transpose: 32 threads per code row, coalesced float4 reads.
    {
        const int k = gid >> 5;
        const int p = gid & 31;
        float4 v0 = E4[(size_t)k * 64 + p * 2];
        float4 v1 = E4[(size_t)k * 64 + p * 2 + 1];
        const int d0 = p * 8;
        ET[(size_t)(d0 + 0) * NK + k] = v0.x; ET[(size_t)(d0 + 1) * NK + k] = v0.y;
        ET[(size_t)(d0 + 2) * NK + k] = v0.z; ET[(size_t)(d0 + 3) * NK + k] = v0.w;
        ET[(size_t)(d0 + 4) * NK + k] = v1.x; ET[(size_t)(d0 + 5) * NK + k] = v1.y;
        ET[(size_t)(d0 + 6) * NK + k] = v1.z; ET[(size_t)(d0 + 7) * NK + k] = v1.w;
    }
    // Merge 4 slices for row n = gid.
    const int n = gid;
    float B1 = b1s[n]; int I1 = i1s[n];
    float B2 = B1 + (float)m12s[n] * 1.0e-8f;
    #pragma unroll
    for (int s = 1; s < NSLICE; ++s) {
        float c1 = b1s[(size_t)s * NN + n];
        float c2 = c1 + (float)m12s[(size_t)s * NN + n] * 1.0e-8f;
        int   ci = i1s[(size_t)s * NN + n];
        if (c1 < B1) { B2 = fminf(B1, c2); B1 = c1; I1 = ci; }  // strict <: lower slice wins ties
        else          B2 = fminf(B2, c1);
    }
    out[IDX_OFF + n] = (float)I1;
    const bool flag = (B2 - B1 < TAU);
    unsigned long long mask = __ballot(flag);
    int wcnt = __popcll(mask);
    int base = 0;
    if ((tid & 63) == 0 && wcnt) base = atomicAdd(cnt, wcnt);
    base = __shfl(base, 0, 64);
    if (flag) {
        int pos = base + __popcll(mask & ((1ull << (tid & 63)) - 1ull));
        list[pos] = (unsigned short)n;
    }
}

// ---------------- Refine: exact fp64 argmin for flagged rows; 8 rows share each E sweep.
// ET[d][k]: lane tid reads 4 consecutive-float streams -> fully coalesced, always.
__global__ __launch_bounds__(256, 2) void vq_refine(const float* __restrict__ X,
                                                    const float* __restrict__ ET,
                                                    const double* __restrict__ e2d,
                                                    const int* __restrict__ cnt,
                                                    const unsigned short* __restrict__ list,
                                                    float* __restrict__ out) {
    __shared__ double xs[8][256];
    __shared__ double sm_s[4][8];
    __shared__ int    sm_k[4][8];
    __shared__ int    sm_n[8];
    const int m = cnt[0];
    const int tid = threadIdx.x;
    for (int j0 = blockIdx.x * 8; j0 < m; j0 += 512 * 8) {
        if (tid < 8) {
            int j = j0 + tid;
            sm_n[tid] = (int)list[j < m ? j : m - 1];
        }
        __syncthreads();
        #pragma unroll
        for (int g = 0; g < 8; ++g) {
            int n = sm_n[g]; int bb = n >> 11; int tt = n & (NT - 1);
            xs[g][tid] = (double)X[((size_t)bb * ND + tid) * NT + tt];
        }
        __syncthreads();
        double acc[4][8];   // [kk][g]
        #pragma unroll
        for (int kk = 0; kk < 4; ++kk)
            #pragma unroll
            for (int g = 0; g < 8; ++g) acc[kk][g] = 0.0;
        for (int dd = 0; dd < 256; ++dd) {
            float e0 = ET[(size_t)dd * NK +   0 + tid];   // coalesced dword loads
            float e1 = ET[(size_t)dd * NK + 256 + tid];
            float e2 = ET[(size_t)dd * NK + 512 + tid];
            float e3 = ET[(size_t)dd * NK + 768 + tid];
            #pragma unroll
            for (int g = 0; g < 8; ++g) {
                double xv = xs[g][dd];                    // LDS broadcast (free)
                acc[0][g] += xv * (double)e0;
                acc[1][g] += xv * (double)e1;
                acc[2][g] += xv * (double)e2;
                acc[3][g] += xv * (double)e3;
            }
        }
        #pragma unroll
        for (int g = 0; g < 8; ++g) {
            double bs = 1e300; int bk = 0x7fffffff;
            #pragma unroll
            for (int kk = 0; kk < 4; ++kk) {
                int k = kk * 256 + tid;
                double s = e2d[k] - 2.0 * acc[kk][g];
                if (s < bs) { bs = s; bk = k; }           // kk ascending: first-index wins
            }
            #pragma unroll
            for (int mm = 1; mm < 64; mm <<= 1) {
                double os = __shfl_xor(bs, mm, 64);
                int    ok = __shfl_xor(bk, mm, 64);
                if (os < bs || (os == bs && ok < bk)) { bs = os; bk = ok; }
            }
            if ((tid & 63) == 0) { sm_s[tid >> 6][g] = bs; sm_k[tid >> 6][g] = bk; }
        }
        __syncthreads();
        if (tid < 8 && j0 + tid < m) {
            double Bv = 1e300; int Kv = 0x7fffffff;
            #pragma unroll
            for (int ww = 0; ww < 4; ++ww) {
                double s2 = sm_s[ww][tid]; int k2 = sm_k[ww][tid];
                if (s2 < Bv || (s2 == Bv && k2 < Kv)) { Bv = s2; Kv = k2; }
            }
            out[IDX_OFF + sm_n[tid]] = (float)Kv;
        }
        __syncthreads();
    }
}

// ---------------- Gather via LDS tile-transpose + per-block MSE partial
__global__ __launch_bounds__(256) void vq_gather(const float* __restrict__ X,
                                                 const float4* __restrict__ E4,
                                                 float* __restrict__ out,
                                                 double* __restrict__ part) {
    __shared__ float Eq[32 * 257];
    __shared__ double sm[4];
    const int bt = blockIdx.x;
    const int b  = bt >> 6;
    const int t0 = (bt & 63) << 5;
    const float* irowf = out + IDX_OFF + b * NT + t0;   // float-encoded indices (exact <=1024)
    {
        const int r  = threadIdx.x >> 3;
        const int l8 = threadIdx.x & 7;
        const int id = (int)irowf[r];
        const float4* er = E4 + (size_t)id * 64;
        #pragma unroll
        for (int it = 0; it < 8; ++it) {
            int c = l8 + (it << 3);
            float4 v = er[c];
            float* p = &Eq[r * 257 + 4 * c];
            p[0] = v.x; p[1] = v.y; p[2] = v.z; p[3] = v.w;
        }
    }
    __syncthreads();
    const int tw = threadIdx.x & 31;
    const int dg = threadIdx.x >> 5;
    double ls = 0.0;
    #pragma unroll 8
    for (int it = 0; it < 32; ++it) {
        const int d = dg + (it << 3);
        const float qv = Eq[tw * 257 + d];
        const size_t off = ((size_t)b * ND + d) * NT + t0 + tw;
        const float x = X[off];
        out[off] = x + (qv - x);             // straight-through, reference rounding
        const double df = (double)qv - (double)x;
        ls = fma(df, df, ls);
    }
    #pragma unroll
    for (int o = 32; o; o >>= 1) ls += __shfl_down(ls, o, 64);
    if ((threadIdx.x & 63) == 0) sm[threadIdx.x >> 6] = ls;
    __syncthreads();
    if (threadIdx.x == 0) part[bt] = sm[0] + sm[1] + sm[2] + sm[3];
}

// ---------------- Finalize: reduce 1024 partials, write scalars
__global__ __launch_bounds__(256) void vq_final(const double* __restrict__ part,
                                                float* __restrict__ out) {
    __shared__ double sm[4];
    const int tid = threadIdx.x;
    double s = part[tid] + part[tid + 256] + part[tid + 512] + part[tid + 768];
    #pragma unroll
    for (int o = 32; o; o >>= 1) s += __shfl_down(s, o, 64);
    if ((tid & 63) == 0) sm[tid >> 6] = s;
    __syncthreads();
    if (tid == 0) {
        double mse = (sm[0] + sm[1] + sm[2] + sm[3]) * (1.0 / (double)QSIZE);
        out[SCL_OFF + 0] = (float)(1.25 * mse);
        out[SCL_OFF + 1] = (float)mse;
        out[SCL_OFF + 2] = (float)mse;
    }
}

extern "C" void kernel_launch(void* const* d_in, const int* in_sizes, int n_in,
                              void* d_out, int out_size, void* d_ws, size_t ws_size,
                              hipStream_t stream) {
    const float* X = (const float*)d_in[0];   // [16, 256, 2048]
    const float* E = (const float*)d_in[1];   // [1024, 256]
    float* out = (float*)d_out;

    char* ws = (char*)d_ws;
    float*  e2f   = (float*) (ws + WS_E2F);
    double* e2d   = (double*)(ws + WS_E2D);
    int*    cnt   = (int*)   (ws + WS_CNT);
    double* part  = (double*)(ws + WS_PART);
    unsigned short* list = (unsigned short*)(ws + WS_LIST);
    float*  b1s   = (float*) (ws + WS_B1S);
    unsigned short* i1s  = (unsigned short*)(ws + WS_I1S);
    unsigned short* m12s = (unsigned short*)(ws + WS_M12);
    uint4*  bpack = (uint4*) (ws + WS_BPACK);
    float*  et    = (float*) (ws + WS_BPACK);   // overlay: Bpack dead after pass1

    vq_prep  <<<NK, 64, 0, stream>>>((const float4*)E, e2d, e2f, bpack, cnt);
    vq_pass1 <<<(NN / 128) * NSLICE, 256, 0, stream>>>(X, bpack, e2f, b1s, i1s, m12s);
    vq_merge <<<NN / 256, 256, 0, stream>>>((const float4*)E, b1s, i1s, m12s, cnt, list, et, out);
    vq_refine<<<512, 256, 0, stream>>>(X, et, e2d, cnt, list, out);
    vq_gather<<<NB * (NT / 32), 256, 0, stream>>>(X, (const float4*)E, out, part);
    vq_final <<<1, 256, 0, stream>>>(part, out);
}

// Round 9
// 200.956 us; speedup vs baseline: 1.8713x; 1.2937x over previous
//
#include <hip/hip_runtime.h>
#include <hip/hip_bf16.h>

// VectorQuantizer: B=16, D=256, T=2048, K=1024, N=B*T=32768
// inputs: [B, D, T] fp32 ; embeddings: [K, D] fp32
// outputs (concat, fp32): quantized_st [B,D,T] | loss | e_latent | q_latent | indices [32768]
#define NB 16
#define ND 256
#define NT 2048
#define NK 1024
#define NN (NB * NT)
#define QSIZE (NB * ND * NT)
#define SCL_OFF QSIZE
#define IDX_OFF (QSIZE + 3)
// bf16-split score error <=~4e-6 worst; TAU=4e-5 (>=5x headroom) -> m ~ 2000 rows refined.
#define TAU 4.0e-5f
#define NSLICE 4          // K-split: 256 codes / slice = 16 chunks of 16 codes

// ws layout (bytes) — 2.08 MB total; proven safe. ET overlays Bpack (dead after pass1).
#define WS_E2F   0         // float[1024]
#define WS_E2D   4096      // double[1024]
#define WS_CNT   12288     // int (+pad)
#define WS_PART  12352     // double[1024]
#define WS_LIST  20544     // ushort[32768]
#define WS_B1S   86080     // float[4][32768] per-slice best
#define WS_I1S   610368    // ushort[4][32768] per-slice argmin
#define WS_M12   872512    // ushort[4][32768] per-slice quantized margin (b2-b1)/1e-8, saturating
#define WS_BPACK 1134656   // 1 MB: B-fragment-packed E (bf16 hi|lo); ET overlays after pass1

typedef __attribute__((ext_vector_type(8))) short bf16x8;
typedef __attribute__((ext_vector_type(4))) float f32x4;
#define MFMA16(a, b, c) __builtin_amdgcn_mfma_f32_16x16x32_bf16(a, b, c, 0, 0, 0)

__device__ inline void bf16split(float v, short& hi, short& lo) {
    union { __hip_bfloat16 b; short s; } uh, ul;
    uh.b = __float2bfloat16(v);
    float hf = __bfloat162float(uh.b);
    ul.b = __float2bfloat16(v - hf);
    hi = uh.s; lo = ul.s;
}

// ---------------- Fused prep: e2[k] (fp64+fp32) + Bpack; zero refine counter.
__global__ __launch_bounds__(64) void vq_prep(const float4* __restrict__ E4,
                                              double* __restrict__ e2d,
                                              float* __restrict__ e2f,
                                              uint4* __restrict__ Bp4,
                                              int* __restrict__ cnt) {
    const int k = blockIdx.x;
    const int lane = threadIdx.x;
    float4 v = E4[k * 64 + lane];
    // Bpack: thread t<32 (ds=t>>2, q=t&3) packs d = ds*32+q*8+{0..7} = row lanes 2t, 2t+1.
    float4 a, b2v;
    a.x = __shfl(v.x, 2 * lane, 64); a.y = __shfl(v.y, 2 * lane, 64);
    a.z = __shfl(v.z, 2 * lane, 64); a.w = __shfl(v.w, 2 * lane, 64);
    b2v.x = __shfl(v.x, 2 * lane + 1, 64); b2v.y = __shfl(v.y, 2 * lane + 1, 64);
    b2v.z = __shfl(v.z, 2 * lane + 1, 64); b2v.w = __shfl(v.w, 2 * lane + 1, 64);
    if (lane < 32) {
        const int ds = lane >> 2, q = lane & 3;
        const int cc = k >> 4;
        const int fl = q * 16 + (k & 15);
        float vals[8] = {a.x, a.y, a.z, a.w, b2v.x, b2v.y, b2v.z, b2v.w};
        union { short s[8]; uint4 u; } hi, lo;
        #pragma unroll
        for (int j = 0; j < 8; ++j) bf16split(vals[j], hi.s[j], lo.s[j]);
        Bp4[(size_t)cc * 1024 + ds * 64 + fl]       = hi.u;
        Bp4[(size_t)cc * 1024 + 512 + ds * 64 + fl] = lo.u;
    }
    double s = (double)v.x * v.x + (double)v.y * v.y + (double)v.z * v.z + (double)v.w * v.w;
    #pragma unroll
    for (int off = 32; off; off >>= 1) s += __shfl_down(s, off, 64);
    if (lane == 0) { e2d[k] = s; e2f[k] = (float)s; }
    if (k == 0 && lane == 0) cnt[0] = 0;
}

// ---------------- Pass 1: 4-way K-split MFMA bf16-split distance GEMM + per-slice argmin.
// grid 1024: slice = bid&3 (16 chunks), rows = (bid>>2)*128. bounds(256,2) — round 7 proved
// forcing 4 waves/EU caps VGPR at 64 and spills. VGPR ~108 fits 4 waves/SIMD naturally.
__global__ __launch_bounds__(256, 2) void vq_pass1(const float* __restrict__ X,
                                                   const uint4* __restrict__ Bp4,
                                                   const float* __restrict__ e2f,
                                                   float* __restrict__ b1s,
                                                   unsigned short* __restrict__ i1s,
                                                   unsigned short* __restrict__ m12s) {
    __shared__ uint4 Bl4[2][1024];   // 32 KB double buffer, chunk = 16 codes
    const int tid   = threadIdx.x;
    const int lane  = tid & 63;
    const int w     = tid >> 6;
    const int slice = blockIdx.x & 3;
    const int n0    = (blockIdx.x >> 2) * 128;
    const int b     = n0 >> 11;
    const int t0    = n0 & (NT - 1);
    const int m16   = lane & 15;
    const int q     = lane >> 4;
    const uint4* Bps = Bp4 + (size_t)slice * 16384;   // 16 chunks x 1024 uint4

    // A fragments: lane holds A[m=lane&15][k=q*8+j] for d = ds*32 + q*8 + j.
    bf16x8 ah[2][8], al[2][8];
    const float* Xb = X + (size_t)b * (ND * NT);
    #pragma unroll
    for (int t = 0; t < 2; ++t) {
        const int trow = t0 + w * 32 + t * 16 + m16;
        #pragma unroll
        for (int ds = 0; ds < 8; ++ds) {
            #pragma unroll
            for (int j = 0; j < 8; ++j) {
                const int d = ds * 32 + q * 8 + j;
                float v = Xb[(size_t)d * NT + trow];
                short h, l; bf16split(v, h, l);
                ah[t][ds][j] = h; al[t][ds][j] = l;
            }
        }
    }

    float b1[2][4], b2[2][4]; int i1[2][4];
    #pragma unroll
    for (int t = 0; t < 2; ++t)
        #pragma unroll
        for (int r = 0; r < 4; ++r) { b1[t][r] = 3e38f; b2[t][r] = 3e38f; i1[t][r] = 0; }

    uint4 pre[4];
    #pragma unroll
    for (int i = 0; i < 4; ++i) pre[i] = Bps[tid + 256 * i];
    #pragma unroll
    for (int i = 0; i < 4; ++i) Bl4[0][tid + 256 * i] = pre[i];
    __syncthreads();

    for (int cc = 0; cc < 16; ++cc) {
        const bf16x8* Bf = (const bf16x8*)Bl4[cc & 1];
        if (cc < 15) {
            #pragma unroll
            for (int i = 0; i < 4; ++i) pre[i] = Bps[(size_t)(cc + 1) * 1024 + tid + 256 * i];
        }
        f32x4 hh0 = {0.f,0.f,0.f,0.f}, lh0 = {0.f,0.f,0.f,0.f}, hl0 = {0.f,0.f,0.f,0.f};
        f32x4 hh1 = {0.f,0.f,0.f,0.f}, lh1 = {0.f,0.f,0.f,0.f}, hl1 = {0.f,0.f,0.f,0.f};
        #pragma unroll
        for (int ds = 0; ds < 8; ++ds) {
            bf16x8 bh = Bf[ds * 64 + lane];
            bf16x8 bl = Bf[512 + ds * 64 + lane];
            hh0 = MFMA16(ah[0][ds], bh, hh0);   // 6 independent chains
            hh1 = MFMA16(ah[1][ds], bh, hh1);
            lh0 = MFMA16(al[0][ds], bh, lh0);
            lh1 = MFMA16(al[1][ds], bh, lh1);
            hl0 = MFMA16(ah[0][ds], bl, hl0);
            hl1 = MFMA16(ah[1][ds], bl, hl1);
        }
        if (cc < 15) {
            #pragma unroll
            for (int i = 0; i < 4; ++i) Bl4[(cc + 1) & 1][tid + 256 * i] = pre[i];
            __syncthreads();
        }
        const int  code = slice * 256 + cc * 16 + m16;
        const float e2v = e2f[code];
        #pragma unroll
        for (int r = 0; r < 4; ++r) {
            float s0 = e2v - 2.0f * (hh0[r] + lh0[r] + hl0[r]);
            if (s0 < b1[0][r]) { b2[0][r] = b1[0][r]; b1[0][r] = s0; i1[0][r] = code; }
            else if (s0 < b2[0][r]) b2[0][r] = s0;
            float s1 = e2v - 2.0f * (hh1[r] + lh1[r] + hl1[r]);
            if (s1 < b1[1][r]) { b2[1][r] = b1[1][r]; b1[1][r] = s1; i1[1][r] = code; }
            else if (s1 < b2[1][r]) b2[1][r] = s1;
        }
    }

    // Reduce across the 16 code-classes; write per-slice candidates (margin quantized).
    #pragma unroll
    for (int t = 0; t < 2; ++t) {
        #pragma unroll
        for (int r = 0; r < 4; ++r) {
            float B1 = b1[t][r], B2 = b2[t][r]; int I1 = i1[t][r];
            #pragma unroll
            for (int mm = 1; mm < 16; mm <<= 1) {
                float o1 = __shfl_xor(B1, mm, 16);
                float o2 = __shfl_xor(B2, mm, 16);
                int   oi = __shfl_xor(I1, mm, 16);
                if (o1 < B1 || (o1 == B1 && oi < I1)) { B2 = fminf(B1, o2); B1 = o1; I1 = oi; }
                else B2 = fminf(B2, o1);
            }
            if (m16 == 0) {
                int n = n0 + w * 32 + t * 16 + q * 4 + r;   // C/D: row = quad*4 + reg
                size_t s = (size_t)slice * NN + n;
                b1s[s] = B1;
                i1s[s] = (unsigned short)I1;
                m12s[s] = (unsigned short)fminf(65535.0f, rintf((B2 - B1) * 1.0e8f));
            }
        }
    }
}

// ---------------- Merge slices -> final index + compacted refine list; also build ET
// (E transposed, overlays dead Bpack) for refine's coalesced float4 reads.
__global__ __launch_bounds__(256) void vq_merge(const float4* __restrict__ E4,
                                                const float* __restrict__ b1s,
                                                const unsigned short* __restrict__ i1s,
                                                const unsigned short* __restrict__ m12s,
                                                int* __restrict__ cnt,
                                                unsigned short* __restrict__ list,
                                                float* __restrict__ ET,
                                                float* __restrict__ out) {
    const int tid = threadIdx.x;
    const int gid = blockIdx.x * 256 + tid;       // 0..32767
    // ET transpose: 32 threads per code row, coalesced float4 reads.
    {
        const int k = gid >> 5;
        const int p = gid & 31;
        float4 v0 = E4[(size_t)k * 64 + p * 2];
        float4 v1 = E4[(size_t)k * 64 + p * 2 + 1];
        const int d0 = p * 8;
        ET[(size_t)(d0 + 0) * NK + k] = v0.x; ET[(size_t)(d0 + 1) * NK + k] = v0.y;
        ET[(size_t)(d0 + 2) * NK + k] = v0.z; ET[(size_t)(d0 + 3) * NK + k] = v0.w;
        ET[(size_t)(d0 + 4) * NK + k] = v1.x; ET[(size_t)(d0 + 5) * NK + k] = v1.y;
        ET[(size_t)(d0 + 6) * NK + k] = v1.z; ET[(size_t)(d0 + 7) * NK + k] = v1.w;
    }
    // Merge 4 slices for row n = gid.
    const int n = gid;
    float B1 = b1s[n]; int I1 = i1s[n];
    float B2 = B1 + (float)m12s[n] * 1.0e-8f;
    #pragma unroll
    for (int s = 1; s < NSLICE; ++s) {
        float c1 = b1s[(size_t)s * NN + n];
        float c2 = c1 + (float)m12s[(size_t)s * NN + n] * 1.0e-8f;
        int   ci = i1s[(size_t)s * NN + n];
        if (c1 < B1) { B2 = fminf(B1, c2); B1 = c1; I1 = ci; }  // strict <: lower slice wins ties
        else          B2 = fminf(B2, c1);
    }
    out[IDX_OFF + n] = (float)I1;
    const bool flag = (B2 - B1 < TAU);
    unsigned long long mask = __ballot(flag);
    int wcnt = __popcll(mask);
    int base = 0;
    if ((tid & 63) == 0 && wcnt) base = atomicAdd(cnt, wcnt);
    base = __shfl(base, 0, 64);
    if (flag) {
        int pos = base + __popcll(mask & ((1ull << (tid & 63)) - 1ull));
        list[pos] = (unsigned short)n;
    }
}

// ---------------- Refine: exact fp64 argmin for flagged rows.
// 2 rows/block -> ~1000 working blocks (~4/CU, 16 waves/CU TLP). Thread owns 4 CONSECUTIVE
// codes (k = 4*tid+kk) so ET reads are one coalesced float4 per dd per thread.
__global__ __launch_bounds__(256, 2) void vq_refine(const float* __restrict__ X,
                                                    const float4* __restrict__ ET4,
                                                    const double* __restrict__ e2d,
                                                    const int* __restrict__ cnt,
                                                    const unsigned short* __restrict__ list,
                                                    float* __restrict__ out) {
    __shared__ double xs[2][256];
    __shared__ double sm_s[4][2];
    __shared__ int    sm_k[4][2];
    __shared__ int    sm_n[2];
    const int m = cnt[0];
    const int tid = threadIdx.x;
    for (int j0 = blockIdx.x * 2; j0 < m; j0 += 2048) {
        if (tid < 2) {
            int j = j0 + tid;
            sm_n[tid] = (int)list[j < m ? j : m - 1];
        }
        __syncthreads();
        #pragma unroll
        for (int g = 0; g < 2; ++g) {
            int n = sm_n[g]; int bb = n >> 11; int tt = n & (NT - 1);
            xs[g][tid] = (double)X[((size_t)bb * ND + tid) * NT + tt];
        }
        __syncthreads();
        double acc[4][2];   // [kk][g], code k = 4*tid + kk
        #pragma unroll
        for (int kk = 0; kk < 4; ++kk) { acc[kk][0] = 0.0; acc[kk][1] = 0.0; }
        #pragma unroll 4
        for (int dd = 0; dd < 256; ++dd) {
            float4 ev = ET4[(size_t)dd * 256 + tid];   // codes 4*tid..4*tid+3, coalesced 16B
            double x0 = xs[0][dd], x1 = xs[1][dd];     // LDS broadcast (free)
            acc[0][0] += x0 * (double)ev.x; acc[0][1] += x1 * (double)ev.x;
            acc[1][0] += x0 * (double)ev.y; acc[1][1] += x1 * (double)ev.y;
            acc[2][0] += x0 * (double)ev.z; acc[2][1] += x1 * (double)ev.z;
            acc[3][0] += x0 * (double)ev.w; acc[3][1] += x1 * (double)ev.w;
        }
        #pragma unroll
        for (int g = 0; g < 2; ++g) {
            double bs = 1e300; int bk = 0x7fffffff;
            #pragma unroll
            for (int kk = 0; kk < 4; ++kk) {
                int k = 4 * tid + kk;
                double s = e2d[k] - 2.0 * acc[kk][g];
                if (s < bs) { bs = s; bk = k; }           // kk ascending: first-index wins
            }
            #pragma unroll
            for (int mm = 1; mm < 64; mm <<= 1) {
                double os = __shfl_xor(bs, mm, 64);
                int    ok = __shfl_xor(bk, mm, 64);
                if (os < bs || (os == bs && ok < bk)) { bs = os; bk = ok; }
            }
            if ((tid & 63) == 0) { sm_s[tid >> 6][g] = bs; sm_k[tid >> 6][g] = bk; }
        }
        __syncthreads();
        if (tid < 2 && j0 + tid < m) {
            double Bv = 1e300; int Kv = 0x7fffffff;
            #pragma unroll
            for (int ww = 0; ww < 4; ++ww) {              // ww ascending = k ascending
                double s2 = sm_s[ww][tid]; int k2 = sm_k[ww][tid];
                if (s2 < Bv || (s2 == Bv && k2 < Kv)) { Bv = s2; Kv = k2; }
            }
            out[IDX_OFF + sm_n[tid]] = (float)Kv;
        }
        __syncthreads();
    }
}

// ---------------- Gather via LDS tile-transpose + per-block MSE partial
__global__ __launch_bounds__(256) void vq_gather(const float* __restrict__ X,
                                                 const float4* __restrict__ E4,
                                                 float* __restrict__ out,
                                                 double* __restrict__ part) {
    __shared__ float Eq[32 * 257];
    __shared__ double sm[4];
    const int bt = blockIdx.x;
    const int b  = bt >> 6;
    const int t0 = (bt & 63) << 5;
    const float* irowf = out + IDX_OFF + b * NT + t0;   // float-encoded indices (exact <=1024)
    {
        const int r  = threadIdx.x >> 3;
        const int l8 = threadIdx.x & 7;
        const int id = (int)irowf[r];
        const float4* er = E4 + (size_t)id * 64;
        #pragma unroll
        for (int it = 0; it < 8; ++it) {
            int c = l8 + (it << 3);
            float4 v = er[c];
            float* p = &Eq[r * 257 + 4 * c];
            p[0] = v.x; p[1] = v.y; p[2] = v.z; p[3] = v.w;
        }
    }
    __syncthreads();
    const int tw = threadIdx.x & 31;
    const int dg = threadIdx.x >> 5;
    double ls = 0.0;
    #pragma unroll 8
    for (int it = 0; it < 32; ++it) {
        const int d = dg + (it << 3);
        const float qv = Eq[tw * 257 + d];
        const size_t off = ((size_t)b * ND + d) * NT + t0 + tw;
        const float x = X[off];
        out[off] = x + (qv - x);             // straight-through, reference rounding
        const double df = (double)qv - (double)x;
        ls = fma(df, df, ls);
    }
    #pragma unroll
    for (int o = 32; o; o >>= 1) ls += __shfl_down(ls, o, 64);
    if ((threadIdx.x & 63) == 0) sm[threadIdx.x >> 6] = ls;
    __syncthreads();
    if (threadIdx.x == 0) part[bt] = sm[0] + sm[1] + sm[2] + sm[3];
}

// ---------------- Finalize: reduce 1024 partials, write scalars
__global__ __launch_bounds__(256) void vq_final(const double* __restrict__ part,
                                                float* __restrict__ out) {
    __shared__ double sm[4];
    const int tid = threadIdx.x;
    double s = part[tid] + part[tid + 256] + part[tid + 512] + part[tid + 768];
    #pragma unroll
    for (int o = 32; o; o >>= 1) s += __shfl_down(s, o, 64);
    if ((tid & 63) == 0) sm[tid >> 6] = s;
    __syncthreads();
    if (tid == 0) {
        double mse = (sm[0] + sm[1] + sm[2] + sm[3]) * (1.0 / (double)QSIZE);
        out[SCL_OFF + 0] = (float)(1.25 * mse);
        out[SCL_OFF + 1] = (float)mse;
        out[SCL_OFF + 2] = (float)mse;
    }
}

extern "C" void kernel_launch(void* const* d_in, const int* in_sizes, int n_in,
                              void* d_out, int out_size, void* d_ws, size_t ws_size,
                              hipStream_t stream) {
    const float* X = (const float*)d_in[0];   // [16, 256, 2048]
    const float* E = (const float*)d_in[1];   // [1024, 256]
    float* out = (float*)d_out;

    char* ws = (char*)d_ws;
    float*  e2f   = (float*) (ws + WS_E2F);
    double* e2d   = (double*)(ws + WS_E2D);
    int*    cnt   = (int*)   (ws + WS_CNT);
    double* part  = (double*)(ws + WS_PART);
    unsigned short* list = (unsigned short*)(ws + WS_LIST);
    float*  b1s   = (float*) (ws + WS_B1S);
    unsigned short* i1s  = (unsigned short*)(ws + WS_I1S);
    unsigned short* m12s = (unsigned short*)(ws + WS_M12);
    uint4*  bpack = (uint4*) (ws + WS_BPACK);
    float*  et    = (float*) (ws + WS_BPACK);   // overlay: Bpack dead after pass1

    vq_prep  <<<NK, 64, 0, stream>>>((const float4*)E, e2d, e2f, bpack, cnt);
    vq_pass1 <<<(NN / 128) * NSLICE, 256, 0, stream>>>(X, bpack, e2f, b1s, i1s, m12s);
    vq_merge <<<NN / 256, 256, 0, stream>>>((const float4*)E, b1s, i1s, m12s, cnt, list, et, out);
    vq_refine<<<1024, 256, 0, stream>>>(X, (const float4*)et, e2d, cnt, list, out);
    vq_gather<<<NB * (NT / 32), 256, 0, stream>>>(X, (const float4*)E, out, part);
    vq_final <<<1, 256, 0, stream>>>(part, out);
}